// Round 5
// baseline (107.948 us; speedup 1.0000x reference)
//
#include <hip/hip_runtime.h>

typedef short short8 __attribute__((ext_vector_type(8)));
typedef float floatx4 __attribute__((ext_vector_type(4)));
typedef float floatx16 __attribute__((ext_vector_type(16)));
typedef unsigned int u32;

#define NEG_SLOPE 0.2f

// pack {bf16_rtne(b), bf16_rtne(a)} into one u32 (a in low half)
__device__ __forceinline__ u32 pk_rtne(float a, float b) {
    u32 ua = __float_as_uint(a); ua += 0x7fffu + ((ua >> 16) & 1u);
    u32 ub = __float_as_uint(b); ub += 0x7fffu + ((ub >> 16) & 1u);
    return __builtin_amdgcn_perm(ub, ua, 0x07060302);
}
// pack {trunc16(b), trunc16(a)} — 1 inst per pair
__device__ __forceinline__ u32 pk_trunc(float a, float b) {
    return __builtin_amdgcn_perm(__float_as_uint(b), __float_as_uint(a), 0x07060302);
}
__device__ __forceinline__ void gl_lds16(const void* g, void* l) {
    __builtin_amdgcn_global_load_lds((__attribute__((address_space(1))) u32*)(void*)g,
                                     (__attribute__((address_space(3))) u32*)l, 16, 0, 0);
}

// ---------------------------------------------------------------------------
// Kernel 0 (R4): k_prep — runs ONCE what k_wh used to replicate 1024x.
// Per head: pack W into 16x16x32 MFMA B-frags (linear layout, 32 KB/head,
// consumed per-lane-coalesced from L2 so no swizzle needed) and compute the
// canonical GEMV vectors V1 = W_h^T a1, V2 = W_h^T a2 (exact same reduction
// tree as the old per-block prologue: per-thread fp32 partials -> shfl_xor(32)
// -> LDS atomicAdd).
// ---------------------------------------------------------------------------
__global__ __launch_bounds__(256, 4) void k_prep(
    const float* __restrict__ W, const float* __restrict__ a,
    unsigned short* __restrict__ WFg, float* __restrict__ V1g,
    float* __restrict__ V2g)
{
    __shared__ float sV1[256], sV2[256];
    const int t = threadIdx.x;
    const int hh = blockIdx.x;              // 4 blocks = 4 heads
    const int lane = t & 63;

    sV1[t] = 0.f;
    sV2[t] = 0.f;
    __syncthreads();

    float vp1[8] = {0, 0, 0, 0, 0, 0, 0, 0};
    float vp2[8] = {0, 0, 0, 0, 0, 0, 0, 0};
    const int c = t & 31;                   // k-chunk of 8 floats
    const int rb = t >> 5;
#pragma unroll
    for (int i = 0; i < 8; ++i) {
        int row = i * 8 + rb;               // d within head
        const float* gp = &W[((size_t)(hh * 64 + row)) * 256 + c * 8];
        float4 w0 = *(const float4*)gp;
        float4 w1 = *(const float4*)(gp + 4);
        float a1r = a[row], a2r = a[64 + row];
        vp1[0] += a1r * w0.x; vp1[1] += a1r * w0.y; vp1[2] += a1r * w0.z; vp1[3] += a1r * w0.w;
        vp1[4] += a1r * w1.x; vp1[5] += a1r * w1.y; vp1[6] += a1r * w1.z; vp1[7] += a1r * w1.w;
        vp2[0] += a2r * w0.x; vp2[1] += a2r * w0.y; vp2[2] += a2r * w0.z; vp2[3] += a2r * w0.w;
        vp2[4] += a2r * w1.x; vp2[5] += a2r * w1.y; vp2[6] += a2r * w1.z; vp2[7] += a2r * w1.w;
        uint4 pv;
        pv.x = pk_rtne(w0.x, w0.y); pv.y = pk_rtne(w0.z, w0.w);
        pv.z = pk_rtne(w1.x, w1.y); pv.w = pk_rtne(w1.z, w1.w);
        int kt = c >> 2, qq = c & 3, nt = row >> 4, r15 = row & 15;
        int idx16 = (kt * 4 + nt) * 64 + qq * 16 + r15;   // linear (no swizzle)
        *(uint4*)&WFg[((size_t)hh * 2048 + idx16) * 8] = pv;
    }
#pragma unroll
    for (int j = 0; j < 8; ++j) {
        vp1[j] += __shfl_xor(vp1[j], 32, 64);
        vp2[j] += __shfl_xor(vp2[j], 32, 64);
    }
    if (lane < 32) {
#pragma unroll
        for (int j = 0; j < 8; ++j) {
            atomicAdd(&sV1[c * 8 + j], vp1[j]);
            atomicAdd(&sV2[c * 8 + j], vp2[j]);
        }
    }
    __syncthreads();
    V1g[hh * 256 + t] = sV1[t];
    V2g[hh * 256 + t] = sV2[t];
}

// ---------------------------------------------------------------------------
// Kernel 1 (R4): Wh = h @ W^T — now ZERO LDS, ZERO barriers, no atomics.
// A-frags from global h; B-frags streamed per-lane-coalesced from the 32 KB
// L2-resident per-head slab WFg; V1/V2 as L1-resident broadcast float4 loads.
// Scores s1/s2 stay EXACT fp32 (h · V). Outputs unchanged:
//  - WhF: Wh^T as pre-swizzled 32x32x16 MFMA *B*-fragments
//    [b4h][jt16(64)][nt32(2)][lane(64)][8 bf16],
//    k-slot permutation pi(g,jj) = (jj&3) + 4*g + 8*(jj>>2)
//  - E1F1[b4h,i] = (exp(s1), exp(0.2*s1)); E2F2[b4h,j] = m_j*(exp(s2), exp(0.2*s2))
// Grid 1024 = 256 mtiles x 4 heads; h-tile sharers stride 256 -> same XCD.
// ---------------------------------------------------------------------------
__global__ __launch_bounds__(256, 4) void k_wh(
    const float* __restrict__ hin, const int* __restrict__ mask,
    const unsigned short* __restrict__ WFg, const float* __restrict__ V1g,
    const float* __restrict__ V2g,
    unsigned short* __restrict__ WhF, float2* __restrict__ E1F1,
    float2* __restrict__ E2F2)
{
    const int t = threadIdx.x;
    const int bi = blockIdx.x;
    const int mtile = bi & 255, hh = bi >> 8;
    const int m0g = mtile * 64;             // global row = b*1024 + i0
    const int b = m0g >> 10, i0 = m0g & 1023;
    const int b4h = b * 4 + hh;
    const int wid = t >> 6, lane = t & 63;
    const int l15 = lane & 15, q = lane >> 4;

    floatx4 acc[4];
#pragma unroll
    for (int nt = 0; nt < 4; ++nt) {
        floatx4 z = {0.f, 0.f, 0.f, 0.f};
        acc[nt] = z;
    }
    float s1a = 0.f, s2a = 0.f;
    const float* hrow = &hin[((size_t)(m0g + wid * 16 + l15)) * 256 + q * 8];
    const unsigned short* wf = &WFg[(size_t)hh * 16384 + (size_t)lane * 8];
    const float* v1 = &V1g[hh * 256 + q * 8];
    const float* v2 = &V2g[hh * 256 + q * 8];
#pragma unroll
    for (int kt = 0; kt < 8; ++kt) {
        float4 h0 = *(const float4*)(hrow + kt * 32);
        float4 h1 = *(const float4*)(hrow + kt * 32 + 4);
        float4 v1a = *(const float4*)(v1 + kt * 32);
        float4 v1b = *(const float4*)(v1 + kt * 32 + 4);
        float4 v2a = *(const float4*)(v2 + kt * 32);
        float4 v2b = *(const float4*)(v2 + kt * 32 + 4);
        s1a += h0.x * v1a.x + h0.y * v1a.y + h0.z * v1a.z + h0.w * v1a.w
             + h1.x * v1b.x + h1.y * v1b.y + h1.z * v1b.z + h1.w * v1b.w;
        s2a += h0.x * v2a.x + h0.y * v2a.y + h0.z * v2a.z + h0.w * v2a.w
             + h1.x * v2b.x + h1.y * v2b.y + h1.z * v2b.z + h1.w * v2b.w;
        union { short8 s; uint4 u; } af;
        af.u.x = pk_rtne(h0.x, h0.y); af.u.y = pk_rtne(h0.z, h0.w);
        af.u.z = pk_rtne(h1.x, h1.y); af.u.w = pk_rtne(h1.z, h1.w);
#pragma unroll
        for (int nt = 0; nt < 4; ++nt) {
            short8 bf = *(const short8*)(wf + (size_t)(kt * 4 + nt) * 512);
            acc[nt] = __builtin_amdgcn_mfma_f32_16x16x32_bf16(af.s, bf, acc[nt], 0, 0, 0);
        }
    }

    // ---- epilogue: store WhF as 32x32x16 B-frags under pi ----
    // source C (16x16): lane(l15,q) holds rows q*4+r, col nt*16+l15.
    const int jt16 = (i0 >> 4) + wid;       // 16-j tile index within head
    const int g = q & 1, jb = (q >> 1) * 4;
#pragma unroll
    for (int nt = 0; nt < 4; ++nt) {
        int nt32 = nt >> 1;
        int l31 = (nt & 1) * 16 + l15;
        uint2 pv;
        pv.x = pk_rtne(acc[nt][0], acc[nt][1]);
        pv.y = pk_rtne(acc[nt][2], acc[nt][3]);
        size_t idx = ((((size_t)b4h * 64 + jt16) * 2 + nt32) * 64 + (g * 32 + l31)) * 8 + jb;
        *(uint2*)&WhF[idx] = pv;
    }

    // ---- scores: fold q (xor 16,32), write E/F ----
    s1a += __shfl_xor(s1a, 16, 64); s1a += __shfl_xor(s1a, 32, 64);
    s2a += __shfl_xor(s2a, 16, 64); s2a += __shfl_xor(s2a, 32, 64);
    if (lane < 16) {
        int i = i0 + wid * 16 + lane;
        E1F1[(size_t)b4h * 1024 + i] = make_float2(__expf(s1a), __expf(NEG_SLOPE * s1a));
        int mj = mask[b * 1024 + i];
        E2F2[(size_t)b4h * 1024 + i] =
            make_float2(mj ? __expf(s2a) : 0.f, mj ? __expf(NEG_SLOPE * s2a) : 0.f);
    }
}

// ---------------------------------------------------------------------------
// Kernel 2: out[i,:] = (sum_j w_ij Wh[j,:]) / (sum_j w_ij),
// w_ij = max(E1_i*E2_j, F1_i*F2_j).  (R3 structure, unchanged — verified.)
// 1024 blocks x 256 thr, block = 64 rows; wave (rg,jh); 16 waves/CU. Wh
// B-frags stream from L2 with 2-deep register prefetch; E/F staged once in
// LDS; zero in-loop barriers; jh-partials pair-reduced through padded LDS.
// ---------------------------------------------------------------------------
__global__ __launch_bounds__(256, 4) void k_attn(
    const int* __restrict__ mask,
    const unsigned short* __restrict__ WhF,
    const float2* __restrict__ E1F1, const float2* __restrict__ E2F2,
    float* __restrict__ out)
{
    __shared__ float2 sEF[1024];             // 8 KB, staged once
    __shared__ float sRed[2][64][49];        // 24.5 KB, pad 48->49: conflict-free

    const int t = threadIdx.x;
    const int bi = blockIdx.x;
    const int b4h = bi & 63, ib = bi >> 6;   // ib 0..15 -> 64-row slice
    const int b = b4h >> 2, hh = b4h & 3;
    const int i0 = ib * 64;
    const int wid = t >> 6, lane = t & 63;
    const int l31 = lane & 31, g = lane >> 5;
    const int rg = wid & 1, jh = wid >> 1;   // row-group, j-half
    const int iw = i0 + rg * 32;

    // stage the whole E2F2 slab (8 KB) once
    {
        const char* src = (const char*)(E2F2 + (size_t)b4h * 1024);
        gl_lds16(src + t * 16, (char*)sEF + t * 16);
        gl_lds16(src + 4096 + t * 16, (char*)sEF + 4096 + t * 16);
    }

    float2 e1 = E1F1[(size_t)b4h * 1024 + iw + l31];   // A-operand row m = l31
    const float E1 = e1.x, F1 = e1.y;

    floatx16 acc0, acc1, accL;
#pragma unroll
    for (int r = 0; r < 16; ++r) { acc0[r] = 0.f; acc1[r] = 0.f; accL[r] = 0.f; }
    const short ob = (short)0x3F80;          // bf16 1.0
    const short8 ones = {ob, ob, ob, ob, ob, ob, ob, ob};

    // per-lane base into the B-fragment slab: chunk c at + c*2048 (+1024 nt=1)
    const char* gbase = (const char*)WhF + (size_t)b4h * 131072 + (size_t)lane * 16;
    const int cb = jh * 32;                  // this wave's chunk window [cb, cb+32)

    // prime 2-deep Wh prefetch (issued before barrier: overlaps sEF staging)
    short8 ga0 = *(const short8*)(gbase + (size_t)cb * 2048);
    short8 ga1 = *(const short8*)(gbase + (size_t)cb * 2048 + 1024);
    short8 gb0 = *(const short8*)(gbase + (size_t)(cb + 1) * 2048);
    short8 gb1 = *(const short8*)(gbase + (size_t)(cb + 1) * 2048 + 1024);

    __syncthreads();                         // sEF ready (drains vmcnt incl. ga/gb)

    // prime E/F (chunk cb)
    float4 nA0, nA1, nB0, nB1;
    {
        const float4* pA = (const float4*)&sEF[cb * 16 + g * 4];
        const float4* pB = (const float4*)&sEF[cb * 16 + 8 + g * 4];
        nA0 = pA[0]; nA1 = pA[1]; nB0 = pB[0]; nB1 = pB[1];
    }

#pragma unroll 4
    for (int cr = 0; cr < 32; cr += 2) {
        // ---- sub-iter A: chunk cb+cr (frags in ga) ----
        {
            const float4 eA0 = nA0, eA1 = nA1, eB0 = nB0, eB1 = nB1;
            const int cn = cb + ((cr + 1) & 31);
            const float4* pA = (const float4*)&sEF[cn * 16 + g * 4];
            const float4* pB = (const float4*)&sEF[cn * 16 + 8 + g * 4];
            nA0 = pA[0]; nA1 = pA[1]; nB0 = pB[0]; nB1 = pB[1];
            const short8 bf0 = ga0, bf1 = ga1;
            const int cg = cb + ((cr + 2) & 31);
            ga0 = *(const short8*)(gbase + (size_t)cg * 2048);
            ga1 = *(const short8*)(gbase + (size_t)cg * 2048 + 1024);
            float w0 = fmaxf(E1 * eA0.x, F1 * eA0.y);
            float w1 = fmaxf(E1 * eA0.z, F1 * eA0.w);
            float w2 = fmaxf(E1 * eA1.x, F1 * eA1.y);
            float w3 = fmaxf(E1 * eA1.z, F1 * eA1.w);
            float w4 = fmaxf(E1 * eB0.x, F1 * eB0.y);
            float w5 = fmaxf(E1 * eB0.z, F1 * eB0.w);
            float w6 = fmaxf(E1 * eB1.x, F1 * eB1.y);
            float w7 = fmaxf(E1 * eB1.z, F1 * eB1.w);
            union { short8 s; u32 u[4]; } af;
            af.u[0] = pk_trunc(w0, w1);
            af.u[1] = pk_trunc(w2, w3);
            af.u[2] = pk_trunc(w4, w5);
            af.u[3] = pk_trunc(w6, w7);
            acc0 = __builtin_amdgcn_mfma_f32_32x32x16_bf16(af.s, bf0, acc0, 0, 0, 0);
            acc1 = __builtin_amdgcn_mfma_f32_32x32x16_bf16(af.s, bf1, acc1, 0, 0, 0);
            accL = __builtin_amdgcn_mfma_f32_32x32x16_bf16(af.s, ones, accL, 0, 0, 0);
        }
        // ---- sub-iter B: chunk cb+cr+1 (frags in gb) ----
        {
            const float4 eA0 = nA0, eA1 = nA1, eB0 = nB0, eB1 = nB1;
            const int cn = cb + ((cr + 2) & 31);
            const float4* pA = (const float4*)&sEF[cn * 16 + g * 4];
            const float4* pB = (const float4*)&sEF[cn * 16 + 8 + g * 4];
            nA0 = pA[0]; nA1 = pA[1]; nB0 = pB[0]; nB1 = pB[1];
            const short8 bf0 = gb0, bf1 = gb1;
            const int cg = cb + ((cr + 3) & 31);
            gb0 = *(const short8*)(gbase + (size_t)cg * 2048);
            gb1 = *(const short8*)(gbase + (size_t)cg * 2048 + 1024);
            float w0 = fmaxf(E1 * eA0.x, F1 * eA0.y);
            float w1 = fmaxf(E1 * eA0.z, F1 * eA0.w);
            float w2 = fmaxf(E1 * eA1.x, F1 * eA1.y);
            float w3 = fmaxf(E1 * eA1.z, F1 * eA1.w);
            float w4 = fmaxf(E1 * eB0.x, F1 * eB0.y);
            float w5 = fmaxf(E1 * eB0.z, F1 * eB0.w);
            float w6 = fmaxf(E1 * eB1.x, F1 * eB1.y);
            float w7 = fmaxf(E1 * eB1.z, F1 * eB1.w);
            union { short8 s; u32 u[4]; } af;
            af.u[0] = pk_trunc(w0, w1);
            af.u[1] = pk_trunc(w2, w3);
            af.u[2] = pk_trunc(w4, w5);
            af.u[3] = pk_trunc(w6, w7);
            acc0 = __builtin_amdgcn_mfma_f32_32x32x16_bf16(af.s, bf0, acc0, 0, 0, 0);
            acc1 = __builtin_amdgcn_mfma_f32_32x32x16_bf16(af.s, bf1, acc1, 0, 0, 0);
            accL = __builtin_amdgcn_mfma_f32_32x32x16_bf16(af.s, ones, accL, 0, 0, 0);
        }
    }

    // ---- pair-reduce jh partials through LDS ----
    if (jh == 1) {
        float* d = &sRed[rg][lane][0];
#pragma unroll
        for (int r = 0; r < 16; ++r) {
            d[r] = acc0[r]; d[16 + r] = acc1[r]; d[32 + r] = accL[r];
        }
    }
    __syncthreads();
    if (jh == 0) {
        const float* d = &sRed[rg][lane][0];
#pragma unroll
        for (int r = 0; r < 16; ++r) {
            acc0[r] += d[r]; acc1[r] += d[16 + r]; accL[r] += d[32 + r];
        }
        // epilogue: C/D 32x32 layout: col = l31, row = (r&3) + 8*(r>>2) + 4*g
#pragma unroll
        for (int r = 0; r < 16; ++r) {
            int row = (r & 3) + 8 * (r >> 2) + 4 * g;
            int i = iw + row;
            float l = accL[r];
            int mi = mask[b * 1024 + i];
            float inv = (mi && l > 0.f) ? 1.0f / l : 0.f;
            size_t o = ((size_t)(b * 1024 + i)) * 256 + hh * 64;
            out[o + l31] = acc0[r] * inv;
            out[o + 32 + l31] = acc1[r] * inv;
        }
    }
}

extern "C" void kernel_launch(void* const* d_in, const int* in_sizes, int n_in,
                              void* d_out, int out_size, void* d_ws, size_t ws_size,
                              hipStream_t stream) {
    const float* h = (const float*)d_in[0];
    const int* mask = (const int*)d_in[1];
    const float* W = (const float*)d_in[2];
    const float* a = (const float*)d_in[3];
    float* out = (float*)d_out;

    // ws: WhF 8 MiB | E1F1 512 KiB | E2F2 512 KiB | WFg 128 KiB | V1g,V2g 4 KiB each
    unsigned short* WhF = (unsigned short*)d_ws;
    float2* E1F1 = (float2*)((char*)d_ws + (size_t)8 * 1024 * 1024);
    float2* E2F2 = E1F1 + 64 * 1024;
    unsigned short* WFg = (unsigned short*)((char*)d_ws + (size_t)9 * 1024 * 1024);
    float* V1g = (float*)((char*)WFg + 4 * 16384 * sizeof(unsigned short));
    float* V2g = V1g + 1024;

    hipLaunchKernelGGL(k_prep, dim3(4), dim3(256), 0, stream, W, a, WFg, V1g, V2g);
    hipLaunchKernelGGL(k_wh, dim3(1024), dim3(256), 0, stream, h, mask, WFg, V1g, V2g, WhF, E1F1, E2F2);
    hipLaunchKernelGGL(k_attn, dim3(1024), dim3(256), 0, stream, mask, WhF, E1F1, E2F2, out);
}

// Round 6
// 99.395 us; speedup vs baseline: 1.0860x; 1.0860x over previous
//
#include <hip/hip_runtime.h>

typedef short short8 __attribute__((ext_vector_type(8)));
typedef float floatx4 __attribute__((ext_vector_type(4)));
typedef float floatx16 __attribute__((ext_vector_type(16)));
typedef unsigned int u32;

#define NEG_SLOPE 0.2f

// pack {bf16_rtne(b), bf16_rtne(a)} into one u32 (a in low half)
__device__ __forceinline__ u32 pk_rtne(float a, float b) {
    u32 ua = __float_as_uint(a); ua += 0x7fffu + ((ua >> 16) & 1u);
    u32 ub = __float_as_uint(b); ub += 0x7fffu + ((ub >> 16) & 1u);
    return __builtin_amdgcn_perm(ub, ua, 0x07060302);
}
// pack {trunc16(b), trunc16(a)} — 1 inst per pair
__device__ __forceinline__ u32 pk_trunc(float a, float b) {
    return __builtin_amdgcn_perm(__float_as_uint(b), __float_as_uint(a), 0x07060302);
}
__device__ __forceinline__ void gl_lds16(const void* g, void* l) {
    __builtin_amdgcn_global_load_lds((__attribute__((address_space(1))) u32*)(void*)g,
                                     (__attribute__((address_space(3))) u32*)l, 16, 0, 0);
}

// ---------------------------------------------------------------------------
// Kernel 0: k_prep (unchanged from R4 — verified) — runs ONCE what k_wh used
// to replicate 1024x. Per head: W packed to 16x16x32 MFMA B-frags (LINEAR
// layout [hh][idx16][8], 32 KB/head) + canonical GEMV vectors V1/V2.
// ---------------------------------------------------------------------------
__global__ __launch_bounds__(256, 4) void k_prep(
    const float* __restrict__ W, const float* __restrict__ a,
    unsigned short* __restrict__ WFg, float* __restrict__ V1g,
    float* __restrict__ V2g)
{
    __shared__ float sV1[256], sV2[256];
    const int t = threadIdx.x;
    const int hh = blockIdx.x;              // 4 blocks = 4 heads
    const int lane = t & 63;

    sV1[t] = 0.f;
    sV2[t] = 0.f;
    __syncthreads();

    float vp1[8] = {0, 0, 0, 0, 0, 0, 0, 0};
    float vp2[8] = {0, 0, 0, 0, 0, 0, 0, 0};
    const int c = t & 31;                   // k-chunk of 8 floats
    const int rb = t >> 5;
#pragma unroll
    for (int i = 0; i < 8; ++i) {
        int row = i * 8 + rb;               // d within head
        const float* gp = &W[((size_t)(hh * 64 + row)) * 256 + c * 8];
        float4 w0 = *(const float4*)gp;
        float4 w1 = *(const float4*)(gp + 4);
        float a1r = a[row], a2r = a[64 + row];
        vp1[0] += a1r * w0.x; vp1[1] += a1r * w0.y; vp1[2] += a1r * w0.z; vp1[3] += a1r * w0.w;
        vp1[4] += a1r * w1.x; vp1[5] += a1r * w1.y; vp1[6] += a1r * w1.z; vp1[7] += a1r * w1.w;
        vp2[0] += a2r * w0.x; vp2[1] += a2r * w0.y; vp2[2] += a2r * w0.z; vp2[3] += a2r * w0.w;
        vp2[4] += a2r * w1.x; vp2[5] += a2r * w1.y; vp2[6] += a2r * w1.z; vp2[7] += a2r * w1.w;
        uint4 pv;
        pv.x = pk_rtne(w0.x, w0.y); pv.y = pk_rtne(w0.z, w0.w);
        pv.z = pk_rtne(w1.x, w1.y); pv.w = pk_rtne(w1.z, w1.w);
        int kt = c >> 2, qq = c & 3, nt = row >> 4, r15 = row & 15;
        int idx16 = (kt * 4 + nt) * 64 + qq * 16 + r15;   // linear (no swizzle)
        *(uint4*)&WFg[((size_t)hh * 2048 + idx16) * 8] = pv;
    }
#pragma unroll
    for (int j = 0; j < 8; ++j) {
        vp1[j] += __shfl_xor(vp1[j], 32, 64);
        vp2[j] += __shfl_xor(vp2[j], 32, 64);
    }
    if (lane < 32) {
#pragma unroll
        for (int j = 0; j < 8; ++j) {
            atomicAdd(&sV1[c * 8 + j], vp1[j]);
            atomicAdd(&sV2[c * 8 + j], vp2[j]);
        }
    }
    __syncthreads();
    V1g[hh * 256 + t] = sV1[t];
    V2g[hh * 256 + t] = sV2[t];
}

// ---------------------------------------------------------------------------
// Kernel 1 (R5): Wh = h @ W^T — R3's LDS-sourced main loop (verified fast),
// but the prologue is now just 9 async gl_lds16 issues + ONE barrier:
//  - sBF  <- WFg (32 KB pre-packed B-frags, linear; XOR swizzle no longer
//    needed since the LDS writes are linear DMA, not scatter stores)
//  - sV1/sV2 <- V1g/V2g (waves 0/1)
// Deleted per block vs R3: ~300 VALU GEMV+pack insts, 16 W float4 loads,
// 16 LDS atomics, 16 shfls, one barrier. Main loop/epilogue arithmetic is
// bit-identical to R3.
// ---------------------------------------------------------------------------
__global__ __launch_bounds__(256, 4) void k_wh(
    const float* __restrict__ hin, const int* __restrict__ mask,
    const unsigned short* __restrict__ WFg, const float* __restrict__ V1g,
    const float* __restrict__ V2g,
    unsigned short* __restrict__ WhF, float2* __restrict__ E1F1,
    float2* __restrict__ E2F2)
{
    __shared__ unsigned short sBF[8 * 4 * 64 * 8];  // 32 KB, linear B-frags
    __shared__ float sV1[256], sV2[256];            // 2 KB

    const int t = threadIdx.x;
    const int bi = blockIdx.x;
    const int mtile = bi & 255, hh = bi >> 8;
    const int m0g = mtile * 64;             // global row = b*1024 + i0
    const int b = m0g >> 10, i0 = m0g & 1023;
    const int b4h = b * 4 + hh;
    const int wid = t >> 6, lane = t & 63;
    const int l15 = lane & 15, q = lane >> 4;

    // ---- async prologue: stage pre-packed W frags + V vectors ----
    {
        const char* wsrc = (const char*)WFg + (size_t)hh * 32768;
#pragma unroll
        for (int r = 0; r < 8; ++r)
            gl_lds16(wsrc + r * 4096 + t * 16, (char*)sBF + r * 4096 + t * 16);
        if (wid == 0)
            gl_lds16((const char*)(V1g + hh * 256) + lane * 16, (char*)sV1 + lane * 16);
        if (wid == 1)
            gl_lds16((const char*)(V2g + hh * 256) + lane * 16, (char*)sV2 + lane * 16);
    }
    __syncthreads();                         // drains vmcnt: sBF/sV ready

    // ---- main loop: A-frags direct from global, no barriers ----
    floatx4 acc[4];
#pragma unroll
    for (int nt = 0; nt < 4; ++nt) {
        floatx4 z = {0.f, 0.f, 0.f, 0.f};
        acc[nt] = z;
    }
    float s1a = 0.f, s2a = 0.f;
    const float* hrow = &hin[((size_t)(m0g + wid * 16 + l15)) * 256 + q * 8];
#pragma unroll
    for (int kt = 0; kt < 8; ++kt) {
        float4 h0 = *(const float4*)(hrow + kt * 32);
        float4 h1 = *(const float4*)(hrow + kt * 32 + 4);
        float4 v1a = *(const float4*)&sV1[kt * 32 + q * 8];
        float4 v1b = *(const float4*)&sV1[kt * 32 + q * 8 + 4];
        float4 v2a = *(const float4*)&sV2[kt * 32 + q * 8];
        float4 v2b = *(const float4*)&sV2[kt * 32 + q * 8 + 4];
        s1a += h0.x * v1a.x + h0.y * v1a.y + h0.z * v1a.z + h0.w * v1a.w
             + h1.x * v1b.x + h1.y * v1b.y + h1.z * v1b.z + h1.w * v1b.w;
        s2a += h0.x * v2a.x + h0.y * v2a.y + h0.z * v2a.z + h0.w * v2a.w
             + h1.x * v2b.x + h1.y * v2b.y + h1.z * v2b.z + h1.w * v2b.w;
        union { short8 s; uint4 u; } af;
        af.u.x = pk_rtne(h0.x, h0.y); af.u.y = pk_rtne(h0.z, h0.w);
        af.u.z = pk_rtne(h1.x, h1.y); af.u.w = pk_rtne(h1.z, h1.w);
#pragma unroll
        for (int nt = 0; nt < 4; ++nt) {
            short8 bf = *(const short8*)&sBF[((kt * 4 + nt) * 64 + lane) * 8];
            acc[nt] = __builtin_amdgcn_mfma_f32_16x16x32_bf16(af.s, bf, acc[nt], 0, 0, 0);
        }
    }

    // ---- epilogue: store WhF as 32x32x16 B-frags under pi ----
    // source C (16x16): lane(l15,q) holds rows q*4+r, col nt*16+l15.
    const int jt16 = (i0 >> 4) + wid;       // 16-j tile index within head
    const int g = q & 1, jb = (q >> 1) * 4;
#pragma unroll
    for (int nt = 0; nt < 4; ++nt) {
        int nt32 = nt >> 1;
        int l31 = (nt & 1) * 16 + l15;
        uint2 pv;
        pv.x = pk_rtne(acc[nt][0], acc[nt][1]);
        pv.y = pk_rtne(acc[nt][2], acc[nt][3]);
        size_t idx = ((((size_t)b4h * 64 + jt16) * 2 + nt32) * 64 + (g * 32 + l31)) * 8 + jb;
        *(uint2*)&WhF[idx] = pv;
    }

    // ---- scores: fold q (xor 16,32), write E/F ----
    s1a += __shfl_xor(s1a, 16, 64); s1a += __shfl_xor(s1a, 32, 64);
    s2a += __shfl_xor(s2a, 16, 64); s2a += __shfl_xor(s2a, 32, 64);
    if (lane < 16) {
        int i = i0 + wid * 16 + lane;
        E1F1[(size_t)b4h * 1024 + i] = make_float2(__expf(s1a), __expf(NEG_SLOPE * s1a));
        int mj = mask[b * 1024 + i];
        E2F2[(size_t)b4h * 1024 + i] =
            make_float2(mj ? __expf(s2a) : 0.f, mj ? __expf(NEG_SLOPE * s2a) : 0.f);
    }
}

// ---------------------------------------------------------------------------
// Kernel 2: out[i,:] = (sum_j w_ij Wh[j,:]) / (sum_j w_ij),
// w_ij = max(E1_i*E2_j, F1_i*F2_j).  (R3 structure, unchanged — verified.)
// 1024 blocks x 256 thr, block = 64 rows; wave (rg,jh); 16 waves/CU. Wh
// B-frags stream from L2 with 2-deep register prefetch; E/F staged once in
// LDS; zero in-loop barriers; jh-partials pair-reduced through padded LDS.
// ---------------------------------------------------------------------------
__global__ __launch_bounds__(256, 4) void k_attn(
    const int* __restrict__ mask,
    const unsigned short* __restrict__ WhF,
    const float2* __restrict__ E1F1, const float2* __restrict__ E2F2,
    float* __restrict__ out)
{
    __shared__ float2 sEF[1024];             // 8 KB, staged once
    __shared__ float sRed[2][64][49];        // 24.5 KB, pad 48->49: conflict-free

    const int t = threadIdx.x;
    const int bi = blockIdx.x;
    const int b4h = bi & 63, ib = bi >> 6;   // ib 0..15 -> 64-row slice
    const int b = b4h >> 2, hh = b4h & 3;
    const int i0 = ib * 64;
    const int wid = t >> 6, lane = t & 63;
    const int l31 = lane & 31, g = lane >> 5;
    const int rg = wid & 1, jh = wid >> 1;   // row-group, j-half
    const int iw = i0 + rg * 32;

    // stage the whole E2F2 slab (8 KB) once
    {
        const char* src = (const char*)(E2F2 + (size_t)b4h * 1024);
        gl_lds16(src + t * 16, (char*)sEF + t * 16);
        gl_lds16(src + 4096 + t * 16, (char*)sEF + 4096 + t * 16);
    }

    float2 e1 = E1F1[(size_t)b4h * 1024 + iw + l31];   // A-operand row m = l31
    const float E1 = e1.x, F1 = e1.y;

    floatx16 acc0, acc1, accL;
#pragma unroll
    for (int r = 0; r < 16; ++r) { acc0[r] = 0.f; acc1[r] = 0.f; accL[r] = 0.f; }
    const short ob = (short)0x3F80;          // bf16 1.0
    const short8 ones = {ob, ob, ob, ob, ob, ob, ob, ob};

    // per-lane base into the B-fragment slab: chunk c at + c*2048 (+1024 nt=1)
    const char* gbase = (const char*)WhF + (size_t)b4h * 131072 + (size_t)lane * 16;
    const int cb = jh * 32;                  // this wave's chunk window [cb, cb+32)

    // prime 2-deep Wh prefetch (issued before barrier: overlaps sEF staging)
    short8 ga0 = *(const short8*)(gbase + (size_t)cb * 2048);
    short8 ga1 = *(const short8*)(gbase + (size_t)cb * 2048 + 1024);
    short8 gb0 = *(const short8*)(gbase + (size_t)(cb + 1) * 2048);
    short8 gb1 = *(const short8*)(gbase + (size_t)(cb + 1) * 2048 + 1024);

    __syncthreads();                         // sEF ready (drains vmcnt incl. ga/gb)

    // prime E/F (chunk cb)
    float4 nA0, nA1, nB0, nB1;
    {
        const float4* pA = (const float4*)&sEF[cb * 16 + g * 4];
        const float4* pB = (const float4*)&sEF[cb * 16 + 8 + g * 4];
        nA0 = pA[0]; nA1 = pA[1]; nB0 = pB[0]; nB1 = pB[1];
    }

#pragma unroll 4
    for (int cr = 0; cr < 32; cr += 2) {
        // ---- sub-iter A: chunk cb+cr (frags in ga) ----
        {
            const float4 eA0 = nA0, eA1 = nA1, eB0 = nB0, eB1 = nB1;
            const int cn = cb + ((cr + 1) & 31);
            const float4* pA = (const float4*)&sEF[cn * 16 + g * 4];
            const float4* pB = (const float4*)&sEF[cn * 16 + 8 + g * 4];
            nA0 = pA[0]; nA1 = pA[1]; nB0 = pB[0]; nB1 = pB[1];
            const short8 bf0 = ga0, bf1 = ga1;
            const int cg = cb + ((cr + 2) & 31);
            ga0 = *(const short8*)(gbase + (size_t)cg * 2048);
            ga1 = *(const short8*)(gbase + (size_t)cg * 2048 + 1024);
            float w0 = fmaxf(E1 * eA0.x, F1 * eA0.y);
            float w1 = fmaxf(E1 * eA0.z, F1 * eA0.w);
            float w2 = fmaxf(E1 * eA1.x, F1 * eA1.y);
            float w3 = fmaxf(E1 * eA1.z, F1 * eA1.w);
            float w4 = fmaxf(E1 * eB0.x, F1 * eB0.y);
            float w5 = fmaxf(E1 * eB0.z, F1 * eB0.w);
            float w6 = fmaxf(E1 * eB1.x, F1 * eB1.y);
            float w7 = fmaxf(E1 * eB1.z, F1 * eB1.w);
            union { short8 s; u32 u[4]; } af;
            af.u[0] = pk_trunc(w0, w1);
            af.u[1] = pk_trunc(w2, w3);
            af.u[2] = pk_trunc(w4, w5);
            af.u[3] = pk_trunc(w6, w7);
            acc0 = __builtin_amdgcn_mfma_f32_32x32x16_bf16(af.s, bf0, acc0, 0, 0, 0);
            acc1 = __builtin_amdgcn_mfma_f32_32x32x16_bf16(af.s, bf1, acc1, 0, 0, 0);
            accL = __builtin_amdgcn_mfma_f32_32x32x16_bf16(af.s, ones, accL, 0, 0, 0);
        }
        // ---- sub-iter B: chunk cb+cr+1 (frags in gb) ----
        {
            const float4 eA0 = nA0, eA1 = nA1, eB0 = nB0, eB1 = nB1;
            const int cn = cb + ((cr + 2) & 31);
            const float4* pA = (const float4*)&sEF[cn * 16 + g * 4];
            const float4* pB = (const float4*)&sEF[cn * 16 + 8 + g * 4];
            nA0 = pA[0]; nA1 = pA[1]; nB0 = pB[0]; nB1 = pB[1];
            const short8 bf0 = gb0, bf1 = gb1;
            const int cg = cb + ((cr + 3) & 31);
            gb0 = *(const short8*)(gbase + (size_t)cg * 2048);
            gb1 = *(const short8*)(gbase + (size_t)cg * 2048 + 1024);
            float w0 = fmaxf(E1 * eA0.x, F1 * eA0.y);
            float w1 = fmaxf(E1 * eA0.z, F1 * eA0.w);
            float w2 = fmaxf(E1 * eA1.x, F1 * eA1.y);
            float w3 = fmaxf(E1 * eA1.z, F1 * eA1.w);
            float w4 = fmaxf(E1 * eB0.x, F1 * eB0.y);
            float w5 = fmaxf(E1 * eB0.z, F1 * eB0.w);
            float w6 = fmaxf(E1 * eB1.x, F1 * eB1.y);
            float w7 = fmaxf(E1 * eB1.z, F1 * eB1.w);
            union { short8 s; u32 u[4]; } af;
            af.u[0] = pk_trunc(w0, w1);
            af.u[1] = pk_trunc(w2, w3);
            af.u[2] = pk_trunc(w4, w5);
            af.u[3] = pk_trunc(w6, w7);
            acc0 = __builtin_amdgcn_mfma_f32_32x32x16_bf16(af.s, bf0, acc0, 0, 0, 0);
            acc1 = __builtin_amdgcn_mfma_f32_32x32x16_bf16(af.s, bf1, acc1, 0, 0, 0);
            accL = __builtin_amdgcn_mfma_f32_32x32x16_bf16(af.s, ones, accL, 0, 0, 0);
        }
    }

    // ---- pair-reduce jh partials through LDS ----
    if (jh == 1) {
        float* d = &sRed[rg][lane][0];
#pragma unroll
        for (int r = 0; r < 16; ++r) {
            d[r] = acc0[r]; d[16 + r] = acc1[r]; d[32 + r] = accL[r];
        }
    }
    __syncthreads();
    if (jh == 0) {
        const float* d = &sRed[rg][lane][0];
#pragma unroll
        for (int r = 0; r < 16; ++r) {
            acc0[r] += d[r]; acc1[r] += d[16 + r]; accL[r] += d[32 + r];
        }
        // epilogue: C/D 32x32 layout: col = l31, row = (r&3) + 8*(r>>2) + 4*g
#pragma unroll
        for (int r = 0; r < 16; ++r) {
            int row = (r & 3) + 8 * (r >> 2) + 4 * g;
            int i = iw + row;
            float l = accL[r];
            int mi = mask[b * 1024 + i];
            float inv = (mi && l > 0.f) ? 1.0f / l : 0.f;
            size_t o = ((size_t)(b * 1024 + i)) * 256 + hh * 64;
            out[o + l31] = acc0[r] * inv;
            out[o + 32 + l31] = acc1[r] * inv;
        }
    }
}

extern "C" void kernel_launch(void* const* d_in, const int* in_sizes, int n_in,
                              void* d_out, int out_size, void* d_ws, size_t ws_size,
                              hipStream_t stream) {
    const float* h = (const float*)d_in[0];
    const int* mask = (const int*)d_in[1];
    const float* W = (const float*)d_in[2];
    const float* a = (const float*)d_in[3];
    float* out = (float*)d_out;

    // ws: WhF 8 MiB | E1F1 512 KiB | E2F2 512 KiB | WFg 128 KiB | V1g,V2g 4 KiB each
    unsigned short* WhF = (unsigned short*)d_ws;
    float2* E1F1 = (float2*)((char*)d_ws + (size_t)8 * 1024 * 1024);
    float2* E2F2 = E1F1 + 64 * 1024;
    unsigned short* WFg = (unsigned short*)((char*)d_ws + (size_t)9 * 1024 * 1024);
    float* V1g = (float*)((char*)WFg + 4 * 16384 * sizeof(unsigned short));
    float* V2g = V1g + 1024;

    hipLaunchKernelGGL(k_prep, dim3(4), dim3(256), 0, stream, W, a, WFg, V1g, V2g);
    hipLaunchKernelGGL(k_wh, dim3(1024), dim3(256), 0, stream, h, mask, WFg, V1g, V2g, WhF, E1F1, E2F2);
    hipLaunchKernelGGL(k_attn, dim3(1024), dim3(256), 0, stream, mask, WhF, E1F1, E2F2, out);
}